// Round 1
// baseline (3851.455 us; speedup 1.0000x reference)
//
#include <hip/hip_runtime.h>
#include <hip/hip_bf16.h>
#include <math.h>

// ---------------------------------------------------------------------------
// FeatureEncoder: 8-layer conv net + instance norm + segment mean. Pure fp32.
// Layer sizes (N=8):
//  L0 conv7x7 reflect3   3->32   256->256
//  L1 conv3x3 s2 p1     32->64   256->128
//  L2 conv3x3 s2 p1     64->128  128->64
//  L3 conv3x3 s2 p1    128->256   64->32
//  L4 convT3x3 s2 p1   256->128   32->63
//  L5 convT3x3 s2 p1   128->64    63->125
//  L6 convT3x3 s2 p1    64->32   125->249
//  L7 conv7x7 reflect3  32->3    249->249  + tanh
//  segment mean over 32 instance ids (batch-pooled, per channel)
// ---------------------------------------------------------------------------

#define IDIV(a, b) (((a) + (b) - 1) / (b))

// ---------------- 7x7 same-conv with reflect padding (pad=3) ----------------
template <int CIN, int OCPT, bool TANH>
__global__ void conv7_reflect(const float* __restrict__ x, const float* __restrict__ w,
                              const float* __restrict__ b, float* __restrict__ y,
                              int H, int W, int Cout) {
    int tx = threadIdx.x & 15, ty = threadIdx.x >> 4;
    int tilesX = (W + 15) >> 4;
    int ow = (blockIdx.x % tilesX) * 16 + tx;
    int oh = (blockIdx.x / tilesX) * 16 + ty;
    int oc0 = blockIdx.y * OCPT;
    int n = blockIdx.z;
    if (ow >= W || oh >= H) return;

    float acc[OCPT];
#pragma unroll
    for (int j = 0; j < OCPT; ++j) acc[j] = 0.f;

    for (int ic = 0; ic < CIN; ++ic) {
        const float* xp = x + ((size_t)(n * CIN + ic)) * H * W;
        for (int kh = 0; kh < 7; ++kh) {
            int ih = oh + kh - 3;
            ih = ih < 0 ? -ih : (ih >= H ? 2 * H - 2 - ih : ih);
            const float* row = xp + (size_t)ih * W;
#pragma unroll
            for (int kw = 0; kw < 7; ++kw) {
                int iw = ow + kw - 3;
                iw = iw < 0 ? -iw : (iw >= W ? 2 * W - 2 - iw : iw);
                float v = row[iw];
#pragma unroll
                for (int j = 0; j < OCPT; ++j)
                    acc[j] += v * w[(((size_t)(oc0 + j) * CIN + ic) * 7 + kh) * 7 + kw];
            }
        }
    }
#pragma unroll
    for (int j = 0; j < OCPT; ++j) {
        float r = acc[j] + b[oc0 + j];
        if (TANH) r = tanhf(r);
        y[(((size_t)n * Cout + oc0 + j) * H + oh) * W + ow] = r;
    }
}

// ---------------- 3x3 stride-2 pad-1 conv ----------------
template <int OCPT>
__global__ void conv3_s2(const float* __restrict__ x, const float* __restrict__ w,
                         const float* __restrict__ b, float* __restrict__ y,
                         int Cin, int Cout, int Hin, int Win, int Hout, int Wout) {
    int tx = threadIdx.x & 15, ty = threadIdx.x >> 4;
    int tilesX = (Wout + 15) >> 4;
    int ow = (blockIdx.x % tilesX) * 16 + tx;
    int oh = (blockIdx.x / tilesX) * 16 + ty;
    int oc0 = blockIdx.y * OCPT;
    int n = blockIdx.z;
    if (ow >= Wout || oh >= Hout) return;

    float acc[OCPT];
#pragma unroll
    for (int j = 0; j < OCPT; ++j) acc[j] = 0.f;

    int ih0 = oh * 2 - 1, iw0 = ow * 2 - 1;
    for (int ic = 0; ic < Cin; ++ic) {
        const float* xp = x + ((size_t)(n * Cin + ic)) * Hin * Win;
        const float* wp = w + ((size_t)oc0 * Cin + ic) * 9;
#pragma unroll
        for (int kh = 0; kh < 3; ++kh) {
            int ih = ih0 + kh;
            if (ih < 0 || ih >= Hin) continue;
#pragma unroll
            for (int kw = 0; kw < 3; ++kw) {
                int iw = iw0 + kw;
                if (iw < 0 || iw >= Win) continue;
                float v = xp[(size_t)ih * Win + iw];
#pragma unroll
                for (int j = 0; j < OCPT; ++j)
                    acc[j] += v * wp[(size_t)j * Cin * 9 + kh * 3 + kw];
            }
        }
    }
#pragma unroll
    for (int j = 0; j < OCPT; ++j)
        y[(((size_t)n * Cout + oc0 + j) * Hout + oh) * Wout + ow] = acc[j] + b[oc0 + j];
}

// ---------------- 3x3 stride-2 pad-1 transposed conv ----------------
// torch ConvTranspose2d weight layout: w[Cin][Cout][3][3].
// y[oh][ow] = sum over taps where d=oh+kh-1 is even, ih=d/2 in range;
//             weight index (2-kh, 2-kw) (flipped kernel).
template <int OCPT>
__global__ void convt3(const float* __restrict__ x, const float* __restrict__ w,
                       const float* __restrict__ b, float* __restrict__ y,
                       int Cin, int Cout, int Hin, int Win, int Hout, int Wout) {
    int tx = threadIdx.x & 15, ty = threadIdx.x >> 4;
    int tilesX = (Wout + 15) >> 4;
    int ow = (blockIdx.x % tilesX) * 16 + tx;
    int oh = (blockIdx.x / tilesX) * 16 + ty;
    int oc0 = blockIdx.y * OCPT;
    int n = blockIdx.z;
    if (ow >= Wout || oh >= Hout) return;

    // tap lists per dimension (1 or 2 taps)
    int ihs[2], khs[2], nH = 0;
#pragma unroll
    for (int kh = 0; kh < 3; ++kh) {
        int d = oh + kh - 1;
        if (!(d & 1) && d >= 0) {
            int ih = d >> 1;
            if (ih < Hin) { ihs[nH] = ih; khs[nH] = kh; ++nH; }
        }
    }
    int iws[2], kws[2], nW = 0;
#pragma unroll
    for (int kw = 0; kw < 3; ++kw) {
        int d = ow + kw - 1;
        if (!(d & 1) && d >= 0) {
            int iw = d >> 1;
            if (iw < Win) { iws[nW] = iw; kws[nW] = kw; ++nW; }
        }
    }

    float acc[OCPT];
#pragma unroll
    for (int j = 0; j < OCPT; ++j) acc[j] = 0.f;

    for (int ic = 0; ic < Cin; ++ic) {
        const float* xp = x + ((size_t)(n * Cin + ic)) * Hin * Win;
        const float* wp = w + ((size_t)ic * Cout + oc0) * 9;
        for (int a = 0; a < nH; ++a) {
            for (int q = 0; q < nW; ++q) {
                float v = xp[(size_t)ihs[a] * Win + iws[q]];
                int widx = (2 - khs[a]) * 3 + (2 - kws[q]);
#pragma unroll
                for (int j = 0; j < OCPT; ++j)
                    acc[j] += v * wp[(size_t)j * 9 + widx];
            }
        }
    }
#pragma unroll
    for (int j = 0; j < OCPT; ++j)
        y[(((size_t)n * Cout + oc0 + j) * Hout + oh) * Wout + ow] = acc[j] + b[oc0 + j];
}

// ---------------- instance norm: stats (mean, rsqrt(var+eps)) ----------------
__global__ void inorm_stats(const float* __restrict__ x, float* __restrict__ mean,
                            float* __restrict__ inv, int plane) {
    int pc = blockIdx.x;
    const float* p = x + (size_t)pc * plane;
    float s = 0.f, ss = 0.f;
    for (int i = threadIdx.x; i < plane; i += 256) {
        float v = p[i];
        s += v;
        ss += v * v;
    }
#pragma unroll
    for (int o = 32; o > 0; o >>= 1) {
        s += __shfl_down(s, o);
        ss += __shfl_down(ss, o);
    }
    __shared__ float sh[8];
    int wid = threadIdx.x >> 6;
    if ((threadIdx.x & 63) == 0) { sh[wid] = s; sh[4 + wid] = ss; }
    __syncthreads();
    if (threadIdx.x == 0) {
        s = sh[0] + sh[1] + sh[2] + sh[3];
        ss = sh[4] + sh[5] + sh[6] + sh[7];
        float m = s / plane;
        float var = ss / plane - m * m;
        mean[pc] = m;
        inv[pc] = rsqrtf(var + 1e-5f);
    }
}

// ---------------- instance norm apply + relu (in place) ----------------
__global__ void inorm_apply(float* __restrict__ x, const float* __restrict__ mean,
                            const float* __restrict__ inv, int plane) {
    int pc = blockIdx.y;
    int i = blockIdx.x * 256 + threadIdx.x;
    if (i >= plane) return;
    float m = mean[pc], iv = inv[pc];
    size_t idx = (size_t)pc * plane + i;
    float v = x[idx];
    x[idx] = fmaxf(0.f, (v - m) * iv);
}

// ---------------- segment mean ----------------
__global__ void seg_zero(float* __restrict__ bins) {
    if (threadIdx.x < 128) bins[threadIdx.x] = 0.f;
}

__global__ void seg_accum(const float* __restrict__ a7, const int* __restrict__ inst,
                          float* __restrict__ bins, int HW) {
    __shared__ float ls[128];  // 96 sums + 32 counts
    for (int i = threadIdx.x; i < 128; i += 256) ls[i] = 0.f;
    __syncthreads();
    int n = blockIdx.y;
    int i = blockIdx.x * 256 + threadIdx.x;
    if (i < HW) {
        int id = inst[(size_t)n * HW + i];
        const float* p = a7 + (size_t)n * 3 * HW + i;
        atomicAdd(&ls[id * 3 + 0], p[0]);
        atomicAdd(&ls[id * 3 + 1], p[HW]);
        atomicAdd(&ls[id * 3 + 2], p[2 * (size_t)HW]);
        atomicAdd(&ls[96 + id], 1.0f);
    }
    __syncthreads();
    for (int i2 = threadIdx.x; i2 < 128; i2 += 256)
        if (ls[i2] != 0.f) atomicAdd(&bins[i2], ls[i2]);
}

__global__ void seg_scatter(const float* __restrict__ bins, const int* __restrict__ inst,
                            float* __restrict__ out, int HW) {
    int n = blockIdx.y;
    int i = blockIdx.x * 256 + threadIdx.x;
    if (i >= HW) return;
    int id = inst[(size_t)n * HW + i];
    float c = fmaxf(bins[96 + id], 1.0f);
    float m0 = bins[id * 3 + 0] / c;
    float m1 = bins[id * 3 + 1] / c;
    float m2 = bins[id * 3 + 2] / c;
    out[((size_t)n * 3 + 0) * HW + i] = m0;
    out[((size_t)n * 3 + 1) * HW + i] = m1;
    out[((size_t)n * 3 + 2) * HW + i] = m2;
}

// ---------------------------------------------------------------------------
extern "C" void kernel_launch(void* const* d_in, const int* in_sizes, int n_in,
                              void* d_out, int out_size, void* d_ws, size_t ws_size,
                              hipStream_t stream) {
    const float* x = (const float*)d_in[0];
    const int* inst = (const int*)d_in[1];
    const float* W[8];
    const float* B[8];
    for (int i = 0; i < 8; ++i) {
        W[i] = (const float*)d_in[2 + 2 * i];
        B[i] = (const float*)d_in[3 + 2 * i];
    }
    float* ws = (float*)d_ws;

    // End-aligned ping-pong arena: S = max over layers of (in + out) elems.
    const size_t S = 25165824;  // 100.66 MB
    float* a0 = ws;                  // 16777216 elems [8,32,256,256]
    float* a1 = ws + 16777216;       //  8388608 elems [8,64,128,128]
    float* a2 = ws;                  //  4194304 elems [8,128,64,64]
    float* a3 = ws + 23068672;       //  2097152 elems [8,256,32,32]
    float* a4 = ws;                  //  4063232 elems [8,128,63,63]
    float* a5 = ws + 17165824;       //  8000000 elems [8,64,125,125]
    float* a6 = ws;                  // 15872256 elems [8,32,249,249]
    float* a7 = ws + 23677800;       //  1488024 elems [8,3,249,249]
    float* mean = ws + S;            // 2048
    float* inv = mean + 2048;        // 2048
    float* bins = inv + 2048;        // 128 (96 sums + 32 counts)

    auto inorm = [&](float* buf, int planes, int plane) {
        inorm_stats<<<dim3(planes), 256, 0, stream>>>(buf, mean, inv, plane);
        inorm_apply<<<dim3(IDIV(plane, 256), planes), 256, 0, stream>>>(buf, mean, inv, plane);
    };

    // L0: 7x7 reflect, 3->32, 256
    conv7_reflect<3, 4, false><<<dim3(256, 8, 8), 256, 0, stream>>>(x, W[0], B[0], a0, 256, 256, 32);
    inorm(a0, 8 * 32, 65536);
    // L1: 3x3 s2, 32->64, 256->128
    conv3_s2<4><<<dim3(64, 16, 8), 256, 0, stream>>>(a0, W[1], B[1], a1, 32, 64, 256, 256, 128, 128);
    inorm(a1, 8 * 64, 16384);
    // L2: 3x3 s2, 64->128, 128->64
    conv3_s2<4><<<dim3(16, 32, 8), 256, 0, stream>>>(a1, W[2], B[2], a2, 64, 128, 128, 128, 64, 64);
    inorm(a2, 8 * 128, 4096);
    // L3: 3x3 s2, 128->256, 64->32
    conv3_s2<4><<<dim3(4, 64, 8), 256, 0, stream>>>(a2, W[3], B[3], a3, 128, 256, 64, 64, 32, 32);
    inorm(a3, 8 * 256, 1024);
    // L4: convT, 256->128, 32->63
    convt3<4><<<dim3(16, 32, 8), 256, 0, stream>>>(a3, W[4], B[4], a4, 256, 128, 32, 32, 63, 63);
    inorm(a4, 8 * 128, 3969);
    // L5: convT, 128->64, 63->125
    convt3<4><<<dim3(64, 16, 8), 256, 0, stream>>>(a4, W[5], B[5], a5, 128, 64, 63, 63, 125, 125);
    inorm(a5, 8 * 64, 15625);
    // L6: convT, 64->32, 125->249
    convt3<4><<<dim3(256, 8, 8), 256, 0, stream>>>(a5, W[6], B[6], a6, 64, 32, 125, 125, 249, 249);
    inorm(a6, 8 * 32, 62001);
    // L7: 7x7 reflect, 32->3, 249, tanh
    conv7_reflect<32, 3, true><<<dim3(256, 1, 8), 256, 0, stream>>>(a6, W[7], B[7], a7, 249, 249, 3);

    // segment mean
    seg_zero<<<1, 128, 0, stream>>>(bins);
    seg_accum<<<dim3(IDIV(62001, 256), 8), 256, 0, stream>>>(a7, inst, bins, 62001);
    seg_scatter<<<dim3(IDIV(62001, 256), 8), 256, 0, stream>>>(bins, inst, (float*)d_out, 62001);
}

// Round 2
// 1996.570 us; speedup vs baseline: 1.9290x; 1.9290x over previous
//
#include <hip/hip_runtime.h>
#include <hip/hip_bf16.h>
#include <math.h>

// ---------------------------------------------------------------------------
// FeatureEncoder: 8-layer conv net + instance norm + segment mean. Pure fp32.
//  L0 conv7x7 reflect3   3->32   256->256
//  L1 conv3x3 s2 p1     32->64   256->128
//  L2 conv3x3 s2 p1     64->128  128->64
//  L3 conv3x3 s2 p1    128->256   64->32
//  L4 convT3x3 s2 p1   256->128   32->63
//  L5 convT3x3 s2 p1   128->64    63->125
//  L6 convT3x3 s2 p1    64->32   125->249
//  L7 conv7x7 reflect3  32->3    249->249  + tanh
//  segment mean over 32 instance ids (batch-pooled, per channel)
//
// R2: convT rewritten as 2x2 output-quad per thread (parity decomposition).
//     All weight indices compile-time constants -> wave-uniform scalar loads;
//     no per-lane divergence. conv3_s2 OCPT 4->8.
// ---------------------------------------------------------------------------

#define IDIV(a, b) (((a) + (b) - 1) / (b))

// ---------------- 7x7 same-conv with reflect padding (pad=3) ----------------
template <int CIN, int OCPT, bool TANH>
__global__ void conv7_reflect(const float* __restrict__ x, const float* __restrict__ w,
                              const float* __restrict__ b, float* __restrict__ y,
                              int H, int W, int Cout) {
    int tx = threadIdx.x & 15, ty = threadIdx.x >> 4;
    int tilesX = (W + 15) >> 4;
    int ow = (blockIdx.x % tilesX) * 16 + tx;
    int oh = (blockIdx.x / tilesX) * 16 + ty;
    int oc0 = blockIdx.y * OCPT;
    int n = blockIdx.z;
    if (ow >= W || oh >= H) return;

    float acc[OCPT];
#pragma unroll
    for (int j = 0; j < OCPT; ++j) acc[j] = 0.f;

    for (int ic = 0; ic < CIN; ++ic) {
        const float* xp = x + ((size_t)(n * CIN + ic)) * H * W;
        for (int kh = 0; kh < 7; ++kh) {
            int ih = oh + kh - 3;
            ih = ih < 0 ? -ih : (ih >= H ? 2 * H - 2 - ih : ih);
            const float* row = xp + (size_t)ih * W;
#pragma unroll
            for (int kw = 0; kw < 7; ++kw) {
                int iw = ow + kw - 3;
                iw = iw < 0 ? -iw : (iw >= W ? 2 * W - 2 - iw : iw);
                float v = row[iw];
#pragma unroll
                for (int j = 0; j < OCPT; ++j)
                    acc[j] += v * w[(((size_t)(oc0 + j) * CIN + ic) * 7 + kh) * 7 + kw];
            }
        }
    }
#pragma unroll
    for (int j = 0; j < OCPT; ++j) {
        float r = acc[j] + b[oc0 + j];
        if (TANH) r = tanhf(r);
        y[(((size_t)n * Cout + oc0 + j) * H + oh) * W + ow] = r;
    }
}

// ---------------- 3x3 stride-2 pad-1 conv ----------------
template <int OCPT>
__global__ void conv3_s2(const float* __restrict__ x, const float* __restrict__ w,
                         const float* __restrict__ b, float* __restrict__ y,
                         int Cin, int Cout, int Hin, int Win, int Hout, int Wout) {
    int tx = threadIdx.x & 15, ty = threadIdx.x >> 4;
    int tilesX = (Wout + 15) >> 4;
    int ow = (blockIdx.x % tilesX) * 16 + tx;
    int oh = (blockIdx.x / tilesX) * 16 + ty;
    int oc0 = blockIdx.y * OCPT;
    int n = blockIdx.z;
    if (ow >= Wout || oh >= Hout) return;

    float acc[OCPT];
#pragma unroll
    for (int j = 0; j < OCPT; ++j) acc[j] = 0.f;

    int ih0 = oh * 2 - 1, iw0 = ow * 2 - 1;
    for (int ic = 0; ic < Cin; ++ic) {
        const float* xp = x + ((size_t)(n * Cin + ic)) * Hin * Win;
        const float* wp = w + ((size_t)oc0 * Cin + ic) * 9;
#pragma unroll
        for (int kh = 0; kh < 3; ++kh) {
            int ih = ih0 + kh;
            if (ih < 0 || ih >= Hin) continue;
#pragma unroll
            for (int kw = 0; kw < 3; ++kw) {
                int iw = iw0 + kw;
                if (iw < 0 || iw >= Win) continue;
                float v = xp[(size_t)ih * Win + iw];
#pragma unroll
                for (int j = 0; j < OCPT; ++j)
                    acc[j] += v * wp[(size_t)j * Cin * 9 + kh * 3 + kw];
            }
        }
    }
#pragma unroll
    for (int j = 0; j < OCPT; ++j)
        y[(((size_t)n * Cout + oc0 + j) * Hout + oh) * Wout + ow] = acc[j] + b[oc0 + j];
}

// ---------------- 3x3 stride-2 pad-1 transposed conv: 2x2 quad form ----------
// torch ConvTranspose2d weight layout: w[Cin][Cout][3][3].
// Output quad (2y,2x),(2y,2x+1),(2y+1,2x),(2y+1,2x+1) consumes input patch
// v00=x[y][x], v01=x[y][x+1], v10=x[y+1][x], v11=x[y+1][x+1]:
//   a00 += w11*v00
//   a01 += w12*v00 + w10*v01
//   a10 += w21*v00 + w01*v10
//   a11 += w22*v00 + w20*v01 + w02*v10 + w00*v11
// All weight indices compile-time -> uniform scalar loads, no divergence.
template <int OCPT>
__global__ void convt3_quad(const float* __restrict__ x, const float* __restrict__ w,
                            const float* __restrict__ b, float* __restrict__ y,
                            int Cin, int Cout, int Hin, int Win, int Hout, int Wout) {
    int tx = threadIdx.x & 15, ty = threadIdx.x >> 4;
    int tilesX = (Win + 15) >> 4;
    int qx = (blockIdx.x % tilesX) * 16 + tx;
    int qy = (blockIdx.x / tilesX) * 16 + ty;
    int oc0 = blockIdx.y * OCPT;
    int n = blockIdx.z;
    if (qx >= Win || qy >= Hin) return;
    bool xin = (qx + 1 < Win);   // also == (2qx+1 < Wout) since Wout = 2Win-1
    bool yin = (qy + 1 < Hin);

    float a00[OCPT], a01[OCPT], a10[OCPT], a11[OCPT];
#pragma unroll
    for (int j = 0; j < OCPT; ++j) { a00[j] = a01[j] = a10[j] = a11[j] = 0.f; }

    const float* xbase = x + ((size_t)n * Cin) * Hin * Win + (size_t)qy * Win + qx;
    for (int ic = 0; ic < Cin; ++ic) {
        const float* xp = xbase + (size_t)ic * Hin * Win;
        float v00 = xp[0];
        float v01 = xin ? xp[1] : 0.f;
        float v10 = yin ? xp[Win] : 0.f;
        float v11 = (xin && yin) ? xp[Win + 1] : 0.f;
        const float* wp = w + ((size_t)ic * Cout + oc0) * 9;
#pragma unroll
        for (int j = 0; j < OCPT; ++j) {
            const float* wj = wp + j * 9;
            float w00 = wj[0], w01 = wj[1], w02 = wj[2];
            float w10 = wj[3], w11 = wj[4], w12 = wj[5];
            float w20 = wj[6], w21 = wj[7], w22 = wj[8];
            a00[j] += w11 * v00;
            a01[j] += w12 * v00 + w10 * v01;
            a10[j] += w21 * v00 + w01 * v10;
            a11[j] += w22 * v00 + w20 * v01 + w02 * v10 + w00 * v11;
        }
    }

    int oh = 2 * qy, ow = 2 * qx;
#pragma unroll
    for (int j = 0; j < OCPT; ++j) {
        float bb = b[oc0 + j];
        float* yp = y + (((size_t)n * Cout + oc0 + j) * Hout + oh) * Wout + ow;
        yp[0] = a00[j] + bb;
        if (xin) yp[1] = a01[j] + bb;
        if (yin) yp[Wout] = a10[j] + bb;
        if (xin && yin) yp[Wout + 1] = a11[j] + bb;
    }
}

// ---------------- instance norm: stats (mean, rsqrt(var+eps)) ----------------
__global__ void inorm_stats(const float* __restrict__ x, float* __restrict__ mean,
                            float* __restrict__ inv, int plane) {
    int pc = blockIdx.x;
    const float* p = x + (size_t)pc * plane;
    float s = 0.f, ss = 0.f;
    for (int i = threadIdx.x; i < plane; i += 256) {
        float v = p[i];
        s += v;
        ss += v * v;
    }
#pragma unroll
    for (int o = 32; o > 0; o >>= 1) {
        s += __shfl_down(s, o);
        ss += __shfl_down(ss, o);
    }
    __shared__ float sh[8];
    int wid = threadIdx.x >> 6;
    if ((threadIdx.x & 63) == 0) { sh[wid] = s; sh[4 + wid] = ss; }
    __syncthreads();
    if (threadIdx.x == 0) {
        s = sh[0] + sh[1] + sh[2] + sh[3];
        ss = sh[4] + sh[5] + sh[6] + sh[7];
        float m = s / plane;
        float var = ss / plane - m * m;
        mean[pc] = m;
        inv[pc] = rsqrtf(var + 1e-5f);
    }
}

// ---------------- instance norm apply + relu (in place) ----------------
__global__ void inorm_apply(float* __restrict__ x, const float* __restrict__ mean,
                            const float* __restrict__ inv, int plane) {
    int pc = blockIdx.y;
    int i = blockIdx.x * 256 + threadIdx.x;
    if (i >= plane) return;
    float m = mean[pc], iv = inv[pc];
    size_t idx = (size_t)pc * plane + i;
    float v = x[idx];
    x[idx] = fmaxf(0.f, (v - m) * iv);
}

// ---------------- segment mean ----------------
__global__ void seg_zero(float* __restrict__ bins) {
    if (threadIdx.x < 128) bins[threadIdx.x] = 0.f;
}

__global__ void seg_accum(const float* __restrict__ a7, const int* __restrict__ inst,
                          float* __restrict__ bins, int HW) {
    __shared__ float ls[128];  // 96 sums + 32 counts
    for (int i = threadIdx.x; i < 128; i += 256) ls[i] = 0.f;
    __syncthreads();
    int n = blockIdx.y;
    int i = blockIdx.x * 256 + threadIdx.x;
    if (i < HW) {
        int id = inst[(size_t)n * HW + i];
        const float* p = a7 + (size_t)n * 3 * HW + i;
        atomicAdd(&ls[id * 3 + 0], p[0]);
        atomicAdd(&ls[id * 3 + 1], p[HW]);
        atomicAdd(&ls[id * 3 + 2], p[2 * (size_t)HW]);
        atomicAdd(&ls[96 + id], 1.0f);
    }
    __syncthreads();
    for (int i2 = threadIdx.x; i2 < 128; i2 += 256)
        if (ls[i2] != 0.f) atomicAdd(&bins[i2], ls[i2]);
}

__global__ void seg_scatter(const float* __restrict__ bins, const int* __restrict__ inst,
                            float* __restrict__ out, int HW) {
    int n = blockIdx.y;
    int i = blockIdx.x * 256 + threadIdx.x;
    if (i >= HW) return;
    int id = inst[(size_t)n * HW + i];
    float c = fmaxf(bins[96 + id], 1.0f);
    float m0 = bins[id * 3 + 0] / c;
    float m1 = bins[id * 3 + 1] / c;
    float m2 = bins[id * 3 + 2] / c;
    out[((size_t)n * 3 + 0) * HW + i] = m0;
    out[((size_t)n * 3 + 1) * HW + i] = m1;
    out[((size_t)n * 3 + 2) * HW + i] = m2;
}

// ---------------------------------------------------------------------------
extern "C" void kernel_launch(void* const* d_in, const int* in_sizes, int n_in,
                              void* d_out, int out_size, void* d_ws, size_t ws_size,
                              hipStream_t stream) {
    const float* x = (const float*)d_in[0];
    const int* inst = (const int*)d_in[1];
    const float* W[8];
    const float* B[8];
    for (int i = 0; i < 8; ++i) {
        W[i] = (const float*)d_in[2 + 2 * i];
        B[i] = (const float*)d_in[3 + 2 * i];
    }
    float* ws = (float*)d_ws;

    // End-aligned ping-pong arena: S = max over layers of (in + out) elems.
    const size_t S = 25165824;  // 100.66 MB
    float* a0 = ws;                  // 16777216 elems [8,32,256,256]
    float* a1 = ws + 16777216;       //  8388608 elems [8,64,128,128]
    float* a2 = ws;                  //  4194304 elems [8,128,64,64]
    float* a3 = ws + 23068672;       //  2097152 elems [8,256,32,32]
    float* a4 = ws;                  //  4063232 elems [8,128,63,63]
    float* a5 = ws + 17165824;       //  8000000 elems [8,64,125,125]
    float* a6 = ws;                  // 15872256 elems [8,32,249,249]
    float* a7 = ws + 23677800;       //  1488024 elems [8,3,249,249]
    float* mean = ws + S;            // 2048
    float* inv = mean + 2048;        // 2048
    float* bins = inv + 2048;        // 128 (96 sums + 32 counts)

    auto inorm = [&](float* buf, int planes, int plane) {
        inorm_stats<<<dim3(planes), 256, 0, stream>>>(buf, mean, inv, plane);
        inorm_apply<<<dim3(IDIV(plane, 256), planes), 256, 0, stream>>>(buf, mean, inv, plane);
    };

    // L0: 7x7 reflect, 3->32, 256
    conv7_reflect<3, 4, false><<<dim3(256, 8, 8), 256, 0, stream>>>(x, W[0], B[0], a0, 256, 256, 32);
    inorm(a0, 8 * 32, 65536);
    // L1: 3x3 s2, 32->64, 256->128
    conv3_s2<8><<<dim3(64, 8, 8), 256, 0, stream>>>(a0, W[1], B[1], a1, 32, 64, 256, 256, 128, 128);
    inorm(a1, 8 * 64, 16384);
    // L2: 3x3 s2, 64->128, 128->64
    conv3_s2<8><<<dim3(16, 16, 8), 256, 0, stream>>>(a1, W[2], B[2], a2, 64, 128, 128, 128, 64, 64);
    inorm(a2, 8 * 128, 4096);
    // L3: 3x3 s2, 128->256, 64->32
    conv3_s2<8><<<dim3(4, 32, 8), 256, 0, stream>>>(a2, W[3], B[3], a3, 128, 256, 64, 64, 32, 32);
    inorm(a3, 8 * 256, 1024);
    // L4: convT, 256->128, in 32x32 -> out 63x63 (quad space 32x32)
    convt3_quad<8><<<dim3(4, 16, 8), 256, 0, stream>>>(a3, W[4], B[4], a4, 256, 128, 32, 32, 63, 63);
    inorm(a4, 8 * 128, 3969);
    // L5: convT, 128->64, in 63x63 -> out 125x125 (quad space 63x63)
    convt3_quad<8><<<dim3(16, 8, 8), 256, 0, stream>>>(a4, W[5], B[5], a5, 128, 64, 63, 63, 125, 125);
    inorm(a5, 8 * 64, 15625);
    // L6: convT, 64->32, in 125x125 -> out 249x249 (quad space 125x125)
    convt3_quad<8><<<dim3(64, 4, 8), 256, 0, stream>>>(a5, W[6], B[6], a6, 64, 32, 125, 125, 249, 249);
    inorm(a6, 8 * 32, 62001);
    // L7: 7x7 reflect, 32->3, 249, tanh
    conv7_reflect<32, 3, true><<<dim3(256, 1, 8), 256, 0, stream>>>(a6, W[7], B[7], a7, 249, 249, 3);

    // segment mean
    seg_zero<<<1, 128, 0, stream>>>(bins);
    seg_accum<<<dim3(IDIV(62001, 256), 8), 256, 0, stream>>>(a7, inst, bins, 62001);
    seg_scatter<<<dim3(IDIV(62001, 256), 8), 256, 0, stream>>>(bins, inst, (float*)d_out, 62001);
}